// Round 5
// baseline (104.889 us; speedup 1.0000x reference)
//
#include <hip/hip_runtime.h>
#include <math.h>

// Problem constants
#define BATCH 32
#define H 512
#define W 512
#define OUT_HW 502           // 512 - 11 + 1
#define TS_X 32              // output strip width
#define BAND 32              // output rows per band
#define NBANDS 16            // full image height per block: 42 + 15*32 = 522 >= 512
#define NTX 16
#define NBLOCKS (NTX * BATCH)    // 512 -> exactly one round at 2 blocks/CU on 256 CUs
#define N1 ((double)BATCH * H * W)
#define N2 ((double)BATCH * OUT_HW * OUT_HW)

// LDS row strides, in halves. R19: padded 48 -> 56 (112 B = 28 banks) to kill
// the 4-way conflicts of stride 48. Keeps b128 16B-alignment.
#define RSTR 56
#define TSTR 56

struct GaussW { float g[11]; };

typedef _Float16 h8  __attribute__((ext_vector_type(8)));
typedef __fp16   h2t __attribute__((ext_vector_type(2)));   // cvt_pkrtz result type
typedef float    f4t __attribute__((ext_vector_type(4)));

// LDS-only barrier: waits DS ops (lgkmcnt) but leaves global loads in flight
// across the barrier. __syncthreads() would emit s_waitcnt vmcnt(0) too,
// draining the phase-1c prefetch right after issue and killing the R17
// pipeline. All cross-thread hazards at these barriers are LDS-only (audit
// below); in-flight globals target per-thread VGPRs, and the compiler still
// waits vmcnt before their consume next band.
__device__ __forceinline__ void barrier_lds()
{
    asm volatile("s_waitcnt lgkmcnt(0)" ::: "memory");
    __builtin_amdgcn_s_barrier();
}

// Launch-bounds history (do not re-break this):
//   (256,3) R1 and (256,4) R3: catastrophic spill. (256,2) R2..R22: sane.
// R13..R16: both 11-tap blurs as banded-Toeplitz MFMA (mfma_f32_16x16x32_f16),
// shared G-fragment B[k][n]=g[k-n]; raw ring (mod 48); rbt transposed
// [col][slot]. R14 NaN lesson: zero-weight MFMA taps still propagate NaN
// (0*NaN=NaN) -- every MFMA-read LDS location must be written or zeroed.
// R16: fp16-packed prep. R17: software-pipelined global loads. R18: tall
// persistent strips (full-height, grid 512 = one round at 2 blocks/CU; XCD
// decode). R19: LDS stride padding. R18/R19 NEUTRAL. R20 WIN (-5.6us):
// h-blur full unroll + 3->2 barriers/band + slim finalize => regime =
// latency/phase-serialization. R21 REGRESSED (+1.3us): ring-rbt work removal
// -- h-blur phase is latency-bound, not throughput-bound; REVERTED.
// R22: per-band barriers changed __syncthreads -> lgkmcnt-only raw barrier so
// the prefetch global loads actually stay in flight across the barrier and
// drain at their consume (next band's prep), not at the barrier.
__global__ __launch_bounds__(256, 2)
void ssim_mfma_kernel(const float* __restrict__ pred,
                      const float* __restrict__ targ,
                      float* __restrict__ ws_contrib,
                      GaussW gw)
{
    __shared__ __align__(16) _Float16 raw[4][48 * RSTR];  // [ch][rowslot*RSTR + px]
    __shared__ __align__(16) _Float16 rbt[4][32 * TSTR];  // [ch][col*TSTR + slot]
    __shared__ float red[8];

    const int tid = threadIdx.x;
    // XCD-binding decode: xcd = bid&7 owns images 4*xcd..4*xcd+3, all 16 tx.
    // Bijective: 512 = 8 xcd * (16 tx * 4 img-slot).
    const int bid = blockIdx.x;
    const int tx  = bid >> 5;
    const int b   = ((bid & 7) << 2) | ((bid >> 3) & 3);
    const int ox0 = tx * TS_X;
    const int cols = min(TS_X, OUT_HW - ox0);     // 32, or 22 for tx=15
    const bool interior_x = (ox0 + 48 <= W);      // full 48-px window in-bounds (tx<=14)

    const float* __restrict__ pb = pred + ((size_t)b << 18);
    const float* __restrict__ tb = targ + ((size_t)b << 18);

    const int lane = tid & 63, wave = tid >> 6;
    const int quad = lane >> 4, nn = lane & 15, quad8 = quad << 3;

    // Per-thread prep item geometry (fixed across bands): row r, 8-px group g
    const int pr = tid / 6, pg = tid - pr * 6;
    const bool pactive = interior_x | (pg < 4);

    // ---- Zero-fill raw (NaN defense: band-0 ring slots 42-47 and tx=15's
    // px 32-47 are MFMA-read but never written; pads also zeroed). rbt needs
    // no fill: h-blur writes every slot/col the v-blur reads, every band.
    {
        _Float16* base = &raw[0][0];
        const int total = 4 * 48 * RSTR;
        for (int i = tid * 8; i < total; i += 256 * 8)
            *(f4t*)(base + i) = f4t{0.f, 0.f, 0.f, 0.f};
    }

    // ---- Constant Toeplitz G fragment: B[k=quad8+j][n=nn] = g[k-n] (0 outside)
    h8 gfrag;
    #pragma unroll
    for (int j = 0; j < 8; ++j) {
        const int kk = quad8 + j - nn;
        float val = 0.f;
        #pragma unroll
        for (int t2 = 0; t2 < 11; ++t2) val = (kk == t2) ? gw.g[t2] : val;
        gfrag[j] = (_Float16)val;
    }
    const f4t zero4 = {0.f, 0.f, 0.f, 0.f};
    const float C1 = 1e-4f, C2 = 9e-4f;

    float mse_local = 0.f, ssim_local = 0.f;

    // V-blur + SSIM epilogue for the band whose output rows start at out0v.
    // Reads rbt only; accumulates into registers only.
    auto do_vblur = [&](int out0v) {
        const int c0 = (wave & 1) << 4, r0v = (wave >> 1) << 4;
        f4t dv2[4];
        #pragma unroll
        for (int ch = 0; ch < 4; ++ch) {
            const h8 a = *(const h8*)&rbt[ch][(c0 + nn) * TSTR + r0v + quad8];
            dv2[ch] = __builtin_amdgcn_mfma_f32_16x16x32_f16(a, gfrag, zero4, 0, 0, 0);
        }
        // D[row=quad*4+reg][col=nn]: out row = out0v+r0v+nn, out px col = c0+quad*4+reg
        const int rowg = out0v + r0v + nn;
        if (rowg < OUT_HW) {
            #pragma unroll
            for (int reg = 0; reg < 4; ++reg) {
                const int cl = c0 + (quad << 2) + reg;
                if (cl < cols) {
                    const float A = dv2[0][reg], Bv = dv2[1][reg];
                    const float U = dv2[2][reg], V  = dv2[3][reg];
                    const float A2 = A * A, B2 = Bv * Bv;
                    const float mu12_2 = 0.5f * (A2 - B2);   // 2*mu1*mu2
                    const float musq   = 0.5f * (A2 + B2);   // mu1^2+mu2^2
                    const float sig12_2 = 0.5f * (U - V) - mu12_2;
                    const float sigsum  = 0.5f * (U + V) - musq;
                    const float num = (mu12_2 + C1) * (sig12_2 + C2);
                    const float den = (musq + C1) * (sigsum + C2) + 1e-6f;
                    ssim_local += num * __builtin_amdgcn_rcpf(den);
                }
            }
        }
    };

    // ---- Prefetch band 0's global data into registers (rows 0..41)
    f4t pf0, pf1, pf2, pf3;
    {
        if ((tid < 42 * 6) & pactive) {
            const int base = (pr << 9) + ox0 + 8 * pg;
            pf0 = *(const f4t*)(pb + base);
            pf1 = *(const f4t*)(pb + base + 4);
            pf2 = *(const f4t*)(tb + base);
            pf3 = *(const f4t*)(tb + base + 4);
        }
    }

    barrier_lds();   // zeros visible before h-blur reads; band-0 loads stay in flight

    // Ring bases (uniform scalars, carried mod 48):
    //   hbase = slot of first NEW row this band, obase = slot of ring row out0
    int hbase = 0, obase = 0;

    // Per band: phase1 { vblur(band-1) | prep(band) | prefetch(band+1) },
    // barrier, phase2 { hblur(band) }, barrier.
    // Ordering audit (all hazards LDS-only => lgkmcnt barrier suffices):
    //   vblur(n-1) reads rbt(n-1)  vs hblur(n) writes rbt : barrier after phase1.
    //   prep(n) writes raw         vs hblur(n) reads raw  : same barrier.
    //   hblur(n-1) reads raw       vs prep(n) writes raw  : barrier after
    //     phase2 of band n-1 (prep only touches NEW ring rows anyway).
    //   vblur/prep within phase1: rbt reads vs raw writes -- disjoint arrays.
    #pragma unroll 1
    for (int band = 0; band < NBANDS; ++band) {
        const int out0 = band * BAND;
        const int h0   = (band == 0) ? 0 : (out0 + 10);   // first NEW raw row
        const int nnew = min(out0 + 42, H) - h0;          // 42 / 32 / 22 (last)

        // ---- Phase 1a: v-blur + SSIM epilogue for the PREVIOUS band
        if (band > 0) do_vblur(out0 - BAND);

        // ---- Phase 1b: consume prefetched registers: fp16-packed prep -> raw
        if ((tid < nnew * 6) & pactive) {
            const h2t hp0 = __builtin_amdgcn_cvt_pkrtz(pf0[0], pf0[1]);
            const h2t hp1 = __builtin_amdgcn_cvt_pkrtz(pf0[2], pf0[3]);
            const h2t hp2 = __builtin_amdgcn_cvt_pkrtz(pf1[0], pf1[1]);
            const h2t hp3 = __builtin_amdgcn_cvt_pkrtz(pf1[2], pf1[3]);
            const h2t ht0 = __builtin_amdgcn_cvt_pkrtz(pf2[0], pf2[1]);
            const h2t ht1 = __builtin_amdgcn_cvt_pkrtz(pf2[2], pf2[3]);
            const h2t ht2 = __builtin_amdgcn_cvt_pkrtz(pf3[0], pf3[1]);
            const h2t ht3 = __builtin_amdgcn_cvt_pkrtz(pf3[2], pf3[3]);
            __align__(16) h2t sv[4], dv[4], ssv[4], ddv[4];
            sv[0] = hp0 + ht0; sv[1] = hp1 + ht1; sv[2] = hp2 + ht2; sv[3] = hp3 + ht3;
            dv[0] = hp0 - ht0; dv[1] = hp1 - ht1; dv[2] = hp2 - ht2; dv[3] = hp3 - ht3;
            ssv[0] = sv[0] * sv[0]; ssv[1] = sv[1] * sv[1];
            ssv[2] = sv[2] * sv[2]; ssv[3] = sv[3] * sv[3];
            ddv[0] = dv[0] * dv[0]; ddv[1] = dv[1] * dv[1];
            ddv[2] = dv[2] * dv[2]; ddv[3] = dv[3] * dv[3];

            // MSE: every loaded row is owned exactly once (no row halo);
            // owned cols are groups 0-3 (ox0..ox0+31).
            if (pg < 4) {
                const h2t macc = (ddv[0] + ddv[1]) + (ddv[2] + ddv[3]);
                mse_local += (float)macc[0] + (float)macc[1];
            }

            int s = hbase + pr;                   // <= 47+41 < 96
            s -= (s >= 48) ? 48 : 0;
            const int off = s * RSTR + 8 * pg;
            *(f4t*)&raw[0][off] = *(const f4t*)sv;
            *(f4t*)&raw[1][off] = *(const f4t*)dv;
            *(f4t*)&raw[2][off] = *(const f4t*)ssv;
            *(f4t*)&raw[3][off] = *(const f4t*)ddv;
        }

        // ---- Phase 1c: prefetch band+1's global data (in flight across the
        // barrier below; drains at next band's phase 1b consume)
        if (band + 1 < NBANDS) {
            const int nh0   = out0 + BAND + 10;
            const int nnnew = min(out0 + BAND + 42, H) - nh0;
            if ((tid < nnnew * 6) & pactive) {
                const int base = ((nh0 + pr) << 9) + ox0 + 8 * pg;
                pf0 = *(const f4t*)(pb + base);
                pf1 = *(const f4t*)(pb + base + 4);
                pf2 = *(const f4t*)(tb + base);
                pf3 = *(const f4t*)(tb + base + 4);
            }
        }
        barrier_lds();   // raw ready; vblur(band-1) rbt reads complete

        // ---- Phase 2: h-blur via MFMA. ch == wave (t5=wave+4k => t5&3==wave);
        // 6 compile-time tiles per wave, fully unrolled: all ds_read_b128
        // issue in one chain, MFMAs drain behind them.
        #pragma unroll
        for (int k = 0; k < 6; ++k) {
            const int j0 = (k & 1) << 4, r0 = (k >> 1) << 4;
            int u = obase + r0 + nn;              // <= 47+32+15 < 96
            u -= (u >= 48) ? 48 : 0;
            const h8 a = *(const h8*)&raw[wave][u * RSTR + j0 + quad8];
            const f4t dacc = __builtin_amdgcn_mfma_f32_16x16x32_f16(a, gfrag, zero4, 0, 0, 0);
            // D[row=quad*4+reg][col=nn]: out col = j0+nn, out slot = r0+quad*4+reg
            h2t* wp = (h2t*)&rbt[wave][(j0 + nn) * TSTR + r0 + (quad << 2)];
            wp[0] = __builtin_amdgcn_cvt_pkrtz(dacc[0], dacc[1]);
            wp[1] = __builtin_amdgcn_cvt_pkrtz(dacc[2], dacc[3]);
        }
        barrier_lds();   // rbt ready for vblur(band) in next phase1

        hbase += nnew;  hbase -= (hbase >= 48) ? 48 : 0;
        obase += BAND;  obase -= (obase >= 48) ? 48 : 0;
    }

    // ---- Last band's v-blur (no following band to merge it into)
    do_vblur((NBANDS - 1) * BAND);

    // ---- Block reduction (256 threads = 4 waves)
    #pragma unroll
    for (int off = 32; off > 0; off >>= 1) {
        ssim_local += __shfl_down(ssim_local, off, 64);
        mse_local  += __shfl_down(mse_local,  off, 64);
    }
    if ((tid & 63) == 0) { red[wave] = ssim_local; red[4 + wave] = mse_local; }
    __syncthreads();
    if (tid == 0) {
        const float s = red[0] + red[1] + red[2] + red[3];
        const float m = red[4] + red[5] + red[6] + red[7];
        const double contrib = 0.6 * (double)m / N1 - 0.4 * (double)s / N2;
        ws_contrib[bid] = (float)contrib;
    }
}

// R20: barrier-free single-wave finalize.
__global__ __launch_bounds__(64)
void finalize_kernel(const float* __restrict__ ws_contrib,
                     float* __restrict__ out)
{
    const int tid = threadIdx.x;
    double s = 0.0;
    #pragma unroll
    for (int i = 0; i < NBLOCKS / 64; ++i)
        s += (double)ws_contrib[tid + i * 64];
    #pragma unroll
    for (int off = 32; off > 0; off >>= 1)
        s += __shfl_down(s, off, 64);
    if (tid == 0)
        out[0] = (float)(0.4 + s);
}

extern "C" void kernel_launch(void* const* d_in, const int* in_sizes, int n_in,
                              void* d_out, int out_size, void* d_ws, size_t ws_size,
                              hipStream_t stream)
{
    const float* pred = (const float*)d_in[0];
    const float* targ = (const float*)d_in[1];
    float* out = (float*)d_out;
    float* ws_contrib = (float*)d_ws;

    // Gaussian taps: computed host-side in double, normalized, passed by value.
    GaussW gw;
    double g[11], sum = 0.0;
    for (int i = 0; i < 11; ++i) { double x = i - 5.0; g[i] = exp(-x * x / 4.5); sum += g[i]; }
    for (int i = 0; i < 11; ++i) gw.g[i] = (float)(g[i] / sum);

    ssim_mfma_kernel<<<dim3(NBLOCKS), 256, 0, stream>>>(pred, targ, ws_contrib, gw);
    finalize_kernel<<<1, 64, 0, stream>>>(ws_contrib, out);
}

// Round 6
// 102.675 us; speedup vs baseline: 1.0216x; 1.0216x over previous
//
#include <hip/hip_runtime.h>
#include <math.h>

// Problem constants
#define BATCH 32
#define H 512
#define W 512
#define OUT_HW 502           // 512 - 11 + 1
#define TS_X 32              // output strip width
#define BAND 32              // output rows per band
#define NBANDS 16            // full image height per block
#define NTX 16
#define NBLOCKS (NTX * BATCH)    // 512 -> one round at 2 blocks/CU on 256 CUs
#define N1 ((double)BATCH * H * W)
#define N2 ((double)BATCH * OUT_HW * OUT_HW)

// LDS row strides, in halves. R19: padded 48 -> 56 (112 B = 28 banks) to kill
// the 4-way conflicts of stride 48. Keeps b128 16B-alignment.
#define RSTR 56
#define TSTR 56
// R23: raw ring depth 48 -> 80 rows so prep(n) (writes rows out0+10..41) and
// hblur(n-1) (real-reads rows out0-32..+9) never alias mod ring within the
// merged phase: row distance in [1,73] < 80.
#define RING 80

struct GaussW { float g[11]; };

typedef _Float16 h8  __attribute__((ext_vector_type(8)));
typedef __fp16   h2t __attribute__((ext_vector_type(2)));   // cvt_pkrtz result type
typedef float    f4t __attribute__((ext_vector_type(4)));

// Launch-bounds history (do not re-break this):
//   (256,3) R1 and (256,4) R3: catastrophic spill. (256,2) R2..R23: sane.
// R13..R16: both 11-tap blurs as banded-Toeplitz MFMA (mfma_f32_16x16x32_f16),
// shared G-fragment B[k][n]=g[k-n]; raw ring; rbt transposed [col][slot].
// R14 NaN lesson: zero-weight MFMA taps still propagate NaN (0*NaN=NaN) --
// every MFMA-read LDS location must be written or zeroed (finite junk OK
// where taps are zero; torn old/new dwords during zero-weight concurrent
// access are finite too).
// R16: fp16-packed prep. R17: software-pipelined global loads. R18: tall
// persistent strips (grid 512, XCD decode). R19: LDS stride padding.
// R18/R19 NEUTRAL. R20 WIN (-5.6us): h-blur full unroll + fewer barriers +
// slim finalize => regime = latency/phase-serialization; fewer phases is THE
// lever. R21 REGRESSED (work removal lengthened critical path; reverted).
// R22 REGRESSED (lgkmcnt-only asm barrier: "memory" clobber conservatism;
// TLP already hid the vmcnt drain; reverted to __syncthreads).
// R23: ONE phase per band: {vblur(n-2) | prep(n) | prefetch(n+1) | hblur(n-1)}
// + one __syncthreads -> 18 barriers (was 32). Enabled by RING=80 raw ring
// (no prep/hblur alias within a phase, see above) and double-buffered rbt
// (hblur(n-1) writes rbt[(n-1)&1], vblur(n-2) reads rbt[n&1]; every read is
// one barrier after its write). Tail: phase16 = hblur(15)+vblur(14),
// phase17 = vblur(15). MSE ownership: 42 + 14*32 + 22 = 512 rows, each once.
__global__ __launch_bounds__(256, 2)
void ssim_mfma_kernel(const float* __restrict__ pred,
                      const float* __restrict__ targ,
                      float* __restrict__ ws_contrib,
                      GaussW gw)
{
    __shared__ __align__(16) _Float16 raw[4][RING * RSTR];   // [ch][slot*RSTR + px]
    __shared__ __align__(16) _Float16 rbt[2][4][32 * TSTR];  // [buf][ch][col*TSTR + slot]
    __shared__ float red[8];

    const int tid = threadIdx.x;
    // XCD-binding decode: xcd = bid&7 owns images 4*xcd..4*xcd+3, all 16 tx.
    // Bijective: 512 = 8 xcd * (16 tx * 4 img-slot).
    const int bid = blockIdx.x;
    const int tx  = bid >> 5;
    const int b   = ((bid & 7) << 2) | ((bid >> 3) & 3);
    const int ox0 = tx * TS_X;
    const int cols = min(TS_X, OUT_HW - ox0);     // 32, or 22 for tx=15
    const bool interior_x = (ox0 + 48 <= W);      // full 48-px window in-bounds (tx<=14)

    const float* __restrict__ pb = pred + ((size_t)b << 18);
    const float* __restrict__ tb = targ + ((size_t)b << 18);

    const int lane = tid & 63, wave = tid >> 6;
    const int quad = lane >> 4, nn = lane & 15, quad8 = quad << 3;

    // Per-thread prep item geometry (fixed across bands): row r, 8-px group g
    const int pr = tid / 6, pg = tid - pr * 6;
    const bool pactive = interior_x | (pg < 4);

    // ---- Zero-fill raw ring (NaN defense: never-written slots -- band-0/1
    // junk tails, band-15 overhang, tx=15's px 32-47 -- are MFMA-read with
    // zero weight and must be finite). rbt needs no fill: hblur fully
    // rewrites the buffer the vblur will read, one barrier earlier.
    {
        _Float16* base = &raw[0][0];
        const int total = 4 * RING * RSTR;
        for (int i = tid * 8; i < total; i += 256 * 8)
            *(f4t*)(base + i) = f4t{0.f, 0.f, 0.f, 0.f};
    }

    // ---- Constant Toeplitz G fragment: B[k=quad8+j][n=nn] = g[k-n] (0 outside)
    h8 gfrag;
    #pragma unroll
    for (int j = 0; j < 8; ++j) {
        const int kk = quad8 + j - nn;
        float val = 0.f;
        #pragma unroll
        for (int t2 = 0; t2 < 11; ++t2) val = (kk == t2) ? gw.g[t2] : val;
        gfrag[j] = (_Float16)val;
    }
    const f4t zero4 = {0.f, 0.f, 0.f, 0.f};
    const float C1 = 1e-4f, C2 = 9e-4f;

    float mse_local = 0.f, ssim_local = 0.f;

    // V-blur + SSIM epilogue for band with output rows from out0v, reading
    // rbt buffer pp. Reads rbt only; accumulates into registers only.
    auto do_vblur = [&](int out0v, int pp) {
        const int c0 = (wave & 1) << 4, r0v = (wave >> 1) << 4;
        f4t dv2[4];
        #pragma unroll
        for (int ch = 0; ch < 4; ++ch) {
            const h8 a = *(const h8*)&rbt[pp][ch][(c0 + nn) * TSTR + r0v + quad8];
            dv2[ch] = __builtin_amdgcn_mfma_f32_16x16x32_f16(a, gfrag, zero4, 0, 0, 0);
        }
        // D[row=quad*4+reg][col=nn]: out row = out0v+r0v+nn, out px col = c0+quad*4+reg
        const int rowg = out0v + r0v + nn;
        if (rowg < OUT_HW) {
            #pragma unroll
            for (int reg = 0; reg < 4; ++reg) {
                const int cl = c0 + (quad << 2) + reg;
                if (cl < cols) {
                    const float A = dv2[0][reg], Bv = dv2[1][reg];
                    const float U = dv2[2][reg], V  = dv2[3][reg];
                    const float A2 = A * A, B2 = Bv * Bv;
                    const float mu12_2 = 0.5f * (A2 - B2);   // 2*mu1*mu2
                    const float musq   = 0.5f * (A2 + B2);   // mu1^2+mu2^2
                    const float sig12_2 = 0.5f * (U - V) - mu12_2;
                    const float sigsum  = 0.5f * (U + V) - musq;
                    const float num = (mu12_2 + C1) * (sig12_2 + C2);
                    const float den = (musq + C1) * (sigsum + C2) + 1e-6f;
                    ssim_local += num * __builtin_amdgcn_rcpf(den);
                }
            }
        }
    };

    // ---- Prefetch band 0's global data into registers (rows 0..41)
    f4t pf0, pf1, pf2, pf3;
    {
        if ((tid < 42 * 6) & pactive) {
            const int base = (pr << 9) + ox0 + 8 * pg;
            pf0 = *(const f4t*)(pb + base);
            pf1 = *(const f4t*)(pb + base + 4);
            pf2 = *(const f4t*)(tb + base);
            pf3 = *(const f4t*)(tb + base + 4);
        }
    }

    __syncthreads();   // zero-fill visible before first prep overwrite / hblur read

    // Ring bases (uniform scalars, carried mod RING):
    //   hb = slot of first NEW raw row for prep(it); ob = slot of row 32*(it-1)
    //   for hblur(it-1).
    int hb = 0, ob = 0;

    // Merged pipeline, one barrier per iteration. Within-phase hazard audit:
    //   prep(it) writes rows out0+10..41; hblur(it-1) real-reads out0-32..+9:
    //     row distance [1,73] < RING=80 -> disjoint slots. Zero-weight tail
    //     rows out0+10..15 are concurrently overwritten: torn-finite, OK.
    //   hblur(it-1) writes rbt[(it-1)&1]; vblur(it-2) reads rbt[it&1]: disjoint.
    //   vblur/prep: disjoint arrays. prefetch: registers only.
    // Cross-phase (one barrier): prep(it) raw writes -> hblur(it) reads;
    //   hblur(it-1) rbt writes -> vblur(it-1) reads; prep(it+1) recycles slots
    //   hblur(it-1) read (distance up to 105 > 80) -- one barrier apart.
    #pragma unroll 1
    for (int it = 0; it < NBANDS + 2; ++it) {
        // ---- vblur(it-2) + SSIM epilogue
        if (it >= 2) do_vblur((it - 2) * BAND, it & 1);

        // ---- prep(it): consume prefetched registers -> raw ring
        if (it < NBANDS) {
            const int nnew = (it == 0) ? 42 : ((it == NBANDS - 1) ? 22 : 32);
            if ((tid < nnew * 6) & pactive) {
                const h2t hp0 = __builtin_amdgcn_cvt_pkrtz(pf0[0], pf0[1]);
                const h2t hp1 = __builtin_amdgcn_cvt_pkrtz(pf0[2], pf0[3]);
                const h2t hp2 = __builtin_amdgcn_cvt_pkrtz(pf1[0], pf1[1]);
                const h2t hp3 = __builtin_amdgcn_cvt_pkrtz(pf1[2], pf1[3]);
                const h2t ht0 = __builtin_amdgcn_cvt_pkrtz(pf2[0], pf2[1]);
                const h2t ht1 = __builtin_amdgcn_cvt_pkrtz(pf2[2], pf2[3]);
                const h2t ht2 = __builtin_amdgcn_cvt_pkrtz(pf3[0], pf3[1]);
                const h2t ht3 = __builtin_amdgcn_cvt_pkrtz(pf3[2], pf3[3]);
                __align__(16) h2t sv[4], dv[4], ssv[4], ddv[4];
                sv[0] = hp0 + ht0; sv[1] = hp1 + ht1; sv[2] = hp2 + ht2; sv[3] = hp3 + ht3;
                dv[0] = hp0 - ht0; dv[1] = hp1 - ht1; dv[2] = hp2 - ht2; dv[3] = hp3 - ht3;
                ssv[0] = sv[0] * sv[0]; ssv[1] = sv[1] * sv[1];
                ssv[2] = sv[2] * sv[2]; ssv[3] = sv[3] * sv[3];
                ddv[0] = dv[0] * dv[0]; ddv[1] = dv[1] * dv[1];
                ddv[2] = dv[2] * dv[2]; ddv[3] = dv[3] * dv[3];

                // MSE: every image row owned by exactly one prep, once.
                if (pg < 4) {
                    const h2t macc = (ddv[0] + ddv[1]) + (ddv[2] + ddv[3]);
                    mse_local += (float)macc[0] + (float)macc[1];
                }

                int s = hb + pr;                  // <= 79+41 < 160
                s -= (s >= RING) ? RING : 0;
                const int off = s * RSTR + 8 * pg;
                *(f4t*)&raw[0][off] = *(const f4t*)sv;
                *(f4t*)&raw[1][off] = *(const f4t*)dv;
                *(f4t*)&raw[2][off] = *(const f4t*)ssv;
                *(f4t*)&raw[3][off] = *(const f4t*)ddv;
            }
        }

        // ---- prefetch(it+1): reload pf regs (consumed next iteration)
        if (it + 1 < NBANDS) {
            const int nh0   = ((it + 1) << 5) + 10;
            const int nnnew = (it + 1 == NBANDS - 1) ? 22 : 32;
            if ((tid < nnnew * 6) & pactive) {
                const int base = ((nh0 + pr) << 9) + ox0 + 8 * pg;
                pf0 = *(const f4t*)(pb + base);
                pf1 = *(const f4t*)(pb + base + 4);
                pf2 = *(const f4t*)(tb + base);
                pf3 = *(const f4t*)(tb + base + 4);
            }
        }

        // ---- hblur(it-1): raw ring rows 32*(it-1) .. +47 -> rbt[(it-1)&1].
        // ch == wave; 6 compile-time tiles, fully unrolled (R20).
        if ((it >= 1) & (it <= NBANDS)) {
            const int hbuf = (it - 1) & 1;
            #pragma unroll
            for (int k = 0; k < 6; ++k) {
                const int j0 = (k & 1) << 4, r0 = (k >> 1) << 4;
                int u = ob + r0 + nn;             // <= 79+32+15 < 160
                u -= (u >= RING) ? RING : 0;
                const h8 a = *(const h8*)&raw[wave][u * RSTR + j0 + quad8];
                const f4t dacc = __builtin_amdgcn_mfma_f32_16x16x32_f16(a, gfrag, zero4, 0, 0, 0);
                // D[row=quad*4+reg][col=nn]: out col = j0+nn, slot = r0+quad*4+reg
                h2t* wp = (h2t*)&rbt[hbuf][wave][(j0 + nn) * TSTR + r0 + (quad << 2)];
                wp[0] = __builtin_amdgcn_cvt_pkrtz(dacc[0], dacc[1]);
                wp[1] = __builtin_amdgcn_cvt_pkrtz(dacc[2], dacc[3]);
            }
        }

        __syncthreads();

        if (it < NBANDS) {
            const int nnew = (it == 0) ? 42 : ((it == NBANDS - 1) ? 22 : 32);
            hb += nnew;  hb -= (hb >= RING) ? RING : 0;
        }
        if (it >= 1) { ob += BAND;  ob -= (ob >= RING) ? RING : 0; }
    }

    // ---- Block reduction (256 threads = 4 waves)
    #pragma unroll
    for (int off = 32; off > 0; off >>= 1) {
        ssim_local += __shfl_down(ssim_local, off, 64);
        mse_local  += __shfl_down(mse_local,  off, 64);
    }
    if ((tid & 63) == 0) { red[wave] = ssim_local; red[4 + wave] = mse_local; }
    __syncthreads();
    if (tid == 0) {
        const float s = red[0] + red[1] + red[2] + red[3];
        const float m = red[4] + red[5] + red[6] + red[7];
        const double contrib = 0.6 * (double)m / N1 - 0.4 * (double)s / N2;
        ws_contrib[bid] = (float)contrib;
    }
}

// R20: barrier-free single-wave finalize.
__global__ __launch_bounds__(64)
void finalize_kernel(const float* __restrict__ ws_contrib,
                     float* __restrict__ out)
{
    const int tid = threadIdx.x;
    double s = 0.0;
    #pragma unroll
    for (int i = 0; i < NBLOCKS / 64; ++i)
        s += (double)ws_contrib[tid + i * 64];
    #pragma unroll
    for (int off = 32; off > 0; off >>= 1)
        s += __shfl_down(s, off, 64);
    if (tid == 0)
        out[0] = (float)(0.4 + s);
}

extern "C" void kernel_launch(void* const* d_in, const int* in_sizes, int n_in,
                              void* d_out, int out_size, void* d_ws, size_t ws_size,
                              hipStream_t stream)
{
    const float* pred = (const float*)d_in[0];
    const float* targ = (const float*)d_in[1];
    float* out = (float*)d_out;
    float* ws_contrib = (float*)d_ws;

    // Gaussian taps: computed host-side in double, normalized, passed by value.
    GaussW gw;
    double g[11], sum = 0.0;
    for (int i = 0; i < 11; ++i) { double x = i - 5.0; g[i] = exp(-x * x / 4.5); sum += g[i]; }
    for (int i = 0; i < 11; ++i) gw.g[i] = (float)(g[i] / sum);

    ssim_mfma_kernel<<<dim3(NBLOCKS), 256, 0, stream>>>(pred, targ, ws_contrib, gw);
    finalize_kernel<<<1, 64, 0, stream>>>(ws_contrib, out);
}